// Round 2
// baseline (615.934 us; speedup 1.0000x reference)
//
#include <hip/hip_runtime.h>

// Levelized STA: L=32 levels, P=131072 pins/level, K=2 fanin arcs.
// d_out layout (floats): [0,LP) arrival | [LP,2LP) required | [2LP,3LP) slack
//                        | [3LP,3LP+NNETS) net mask as 0.0/1.0
// NOTE: the harness delivers the JAX bool mask as int32 (one int per net).
constexpr int L = 32;
constexpr int P = 131072;
constexpr int LP = L * P;
constexpr int NNETS = 1000000;
constexpr float TPER = 10.0f;
constexpr float NEGV = -1e30f;

// Float atomic-min via int-min (val>=0) / uint-max (val<0). Correct for all
// sign combinations: IEEE-754 total order maps to signed-int order for
// non-negative floats and to reversed unsigned order for negative floats.
__device__ __forceinline__ void atomic_min_f32(float* addr, float val) {
  if (val >= 0.0f) {
    atomicMin(reinterpret_cast<int*>(addr), __float_as_int(val));
  } else {
    atomicMax(reinterpret_cast<unsigned int*>(addr), __float_as_uint(val));
  }
}

// Init: required[all L*P] = TPER, arrival[level 0] = delays[level 0],
// mask tail copied out as float 0/1. d_out is poisoned 0xAA before every
// call, so this must run every call.
__global__ __launch_bounds__(256) void sta_init(
    const float* __restrict__ delays, const int* __restrict__ mask,
    float* __restrict__ out) {
  int i4 = (blockIdx.x * blockDim.x + threadIdx.x) * 4;
  if (i4 < LP) {
    float4 ten = {TPER, TPER, TPER, TPER};
    *reinterpret_cast<float4*>(out + LP + i4) = ten;
    if (i4 < P) {
      *reinterpret_cast<float4*>(out + i4) =
          *reinterpret_cast<const float4*>(delays + i4);
    }
  }
  if (i4 < NNETS) {  // NNETS % 4 == 0
    int4 m = *reinterpret_cast<const int4*>(mask + i4);
    float4 f = {(float)(m.x != 0), (float)(m.y != 0), (float)(m.z != 0),
                (float)(m.w != 0)};
    *reinterpret_cast<float4*>(out + 3 * LP + i4) = f;
  }
}

// Fused step i (1..31): forward arrival level lf=i (gather-max from lf-1),
// backward required level lb=L-1-i (scatter-min from lb+1). The two chains
// are independent; kernel boundaries provide the level-to-level ordering.
__global__ __launch_bounds__(256) void sta_step(
    const float* __restrict__ delays, const int* __restrict__ src,
    const int* __restrict__ net, const int* __restrict__ mask,
    float* __restrict__ out, int i) {
  const int p = blockIdx.x * blockDim.x + threadIdx.x;  // one pin per thread
  float* arr = out;
  float* req = out + LP;
  const int lf = i;
  const int lb = L - 1 - i;

  // ---- forward: arrival[lf][p] = max(max over valid fanin, own delay) ----
  {
    const float d = delays[lf * P + p];
    const int2 s = *reinterpret_cast<const int2*>(src + (size_t)(lf - 1) * P * 2 + p * 2);
    const int2 n = *reinterpret_cast<const int2*>(net + (size_t)(lf - 1) * P * 2 + p * 2);
    const float* ap = arr + (lf - 1) * P;
    const float v0 = mask[n.x] ? NEGV : ap[s.x] + d;
    const float v1 = mask[n.y] ? NEGV : ap[s.y] + d;
    arr[lf * P + p] = fmaxf(fmaxf(v0, v1), d);
  }

  // ---- backward: scatter-min into required[lb] from required[lb+1] ----
  {
    const float d = delays[(lb + 1) * P + p];
    const float r = req[(lb + 1) * P + p];
    const float c = r - d;
    const int2 s = *reinterpret_cast<const int2*>(src + (size_t)lb * P * 2 + p * 2);
    const int2 n = *reinterpret_cast<const int2*>(net + (size_t)lb * P * 2 + p * 2);
    float* rp = req + lb * P;
    if (!mask[n.x]) atomic_min_f32(rp + s.x, c);
    if (!mask[n.y]) atomic_min_f32(rp + s.y, c);
  }
}

// Epilogue: slack = required - arrival.
__global__ __launch_bounds__(256) void sta_slack(float* __restrict__ out) {
  int i4 = (blockIdx.x * blockDim.x + threadIdx.x) * 4;
  if (i4 < LP) {
    float4 a = *reinterpret_cast<const float4*>(out + i4);
    float4 r = *reinterpret_cast<const float4*>(out + LP + i4);
    float4 s = {r.x - a.x, r.y - a.y, r.z - a.z, r.w - a.w};
    *reinterpret_cast<float4*>(out + 2 * LP + i4) = s;
  }
}

extern "C" void kernel_launch(void* const* d_in, const int* in_sizes, int n_in,
                              void* d_out, int out_size, void* d_ws, size_t ws_size,
                              hipStream_t stream) {
  const float* delays = (const float*)d_in[0];
  const int* src = (const int*)d_in[1];
  const int* net = (const int*)d_in[2];
  const int* mask = (const int*)d_in[3];  // JAX bool delivered as int32
  float* out = (float*)d_out;

  // init: LP/4 threads cover both the req region and the mask tail
  sta_init<<<LP / 1024, 256, 0, stream>>>(delays, mask, out);
  // 31 fused forward/backward steps (serial dependency chain)
  for (int i = 1; i < L; ++i) {
    sta_step<<<P / 256, 256, 0, stream>>>(delays, src, net, mask, out, i);
  }
  sta_slack<<<LP / 1024, 256, 0, stream>>>(out);
}

// Round 4
// 593.684 us; speedup vs baseline: 1.0375x; 1.0375x over previous
//
#include <hip/hip_runtime.h>

// Levelized STA: L=32 levels, P=131072 pins/level, K=2 fanin arcs.
// d_out layout (floats): [0,LP) arrival | [LP,2LP) required | [2LP,3LP) slack
//                        | [3LP,3LP+NNETS) net mask as 0.0/1.0
// d_ws: esrc[(L-1)*P*2] int32 = src index with bit31 = "arc invalid (ignored net)".
// NOTE: the harness delivers the JAX bool mask as int32 (one int per net).
constexpr int L = 32;
constexpr int P = 131072;           // 2^17
constexpr int LP = L * P;
constexpr int NARC = (L - 1) * P * 2;  // 8,126,464 (divisible by 4)
constexpr int NNETS = 1000000;
constexpr float TPER = 10.0f;
constexpr float NEGV = -1e30f;
constexpr int SRCMASK = P - 1;      // 0x1FFFF

// Float atomic-min via int-min (val>=0) / uint-max (val<0). Correct for all
// sign combinations under IEEE-754 ordering. Init value (TPER) is positive.
__device__ __forceinline__ void atomic_min_f32(float* addr, float val) {
  if (val >= 0.0f) {
    atomicMin(reinterpret_cast<int*>(addr), __float_as_int(val));
  } else {
    atomicMax(reinterpret_cast<unsigned int*>(addr), __float_as_uint(val));
  }
}

// Precompute: fold the net-ignore mask into the source index (bit 31).
// 8.1M random mask lookups done ONCE, fully parallel, off the serial chain.
__global__ __launch_bounds__(256) void sta_pre(
    const int* __restrict__ src, const int* __restrict__ net,
    const int* __restrict__ mask, int* __restrict__ esrc) {
  int a4 = (blockIdx.x * blockDim.x + threadIdx.x) * 4;
  if (a4 < NARC) {
    int4 s = *reinterpret_cast<const int4*>(src + a4);
    int4 n = *reinterpret_cast<const int4*>(net + a4);
    s.x |= mask[n.x] ? 0x80000000 : 0;
    s.y |= mask[n.y] ? 0x80000000 : 0;
    s.z |= mask[n.z] ? 0x80000000 : 0;
    s.w |= mask[n.w] ? 0x80000000 : 0;
    *reinterpret_cast<int4*>(esrc + a4) = s;
  }
}

// Init: required[all L*P] = TPER, arrival[level 0] = delays[level 0],
// mask tail copied out as float 0/1. d_out is poisoned before every call.
__global__ __launch_bounds__(256) void sta_init(
    const float* __restrict__ delays, const int* __restrict__ mask,
    float* __restrict__ out) {
  int i4 = (blockIdx.x * blockDim.x + threadIdx.x) * 4;
  if (i4 < LP) {
    float4 ten = {TPER, TPER, TPER, TPER};
    *reinterpret_cast<float4*>(out + LP + i4) = ten;
    if (i4 < P) {
      *reinterpret_cast<float4*>(out + i4) =
          *reinterpret_cast<const float4*>(delays + i4);
    }
  }
  if (i4 < NNETS) {  // NNETS % 4 == 0
    int4 m = *reinterpret_cast<const int4*>(mask + i4);
    float4 f = {(float)(m.x != 0), (float)(m.y != 0), (float)(m.z != 0),
                (float)(m.w != 0)};
    *reinterpret_cast<float4*>(out + 3 * LP + i4) = f;
  }
}

// Fused step i (1..31): threads [0,P) = forward level lf=i (gather-max from
// lf-1); threads [P,2P) = backward scatter-min into req[lb] from req[lb+1],
// lb=L-1-i. Disjoint thread ranges -> 2x TLP, block-granular divergence only.
__global__ __launch_bounds__(256) void sta_step(
    const float* __restrict__ delays, const int* __restrict__ esrc,
    float* __restrict__ out, int i) {
  const int t = blockIdx.x * blockDim.x + threadIdx.x;
  float* arr = out;
  float* req = out + LP;
  const int lf = i;
  const int lb = L - 1 - i;
  if (t < P) {
    const int p = t;
    const float d = delays[lf * P + p];
    const int2 s = *reinterpret_cast<const int2*>(esrc + (size_t)(lf - 1) * P * 2 + p * 2);
    const float* ap = arr + (lf - 1) * P;
    float v0 = ap[s.x & SRCMASK] + d;  // branchless: invalid arcs gather junk
    float v1 = ap[s.y & SRCMASK] + d;
    v0 = (s.x < 0) ? NEGV : v0;        // ...then get cndmask'd to NEG
    v1 = (s.y < 0) ? NEGV : v1;
    arr[lf * P + p] = fmaxf(fmaxf(v0, v1), d);
  } else {
    const int p = t - P;
    const float c = req[(lb + 1) * P + p] - delays[(lb + 1) * P + p];
    const int2 s = *reinterpret_cast<const int2*>(esrc + (size_t)lb * P * 2 + p * 2);
    float* rp = req + lb * P;
    if (s.x >= 0) atomic_min_f32(rp + s.x, c);  // bit31 clear => s IS the index
    if (s.y >= 0) atomic_min_f32(rp + s.y, c);
  }
}

// Fallback step (R2-proven path) if ws_size is ever too small for esrc.
__global__ __launch_bounds__(256) void sta_step_direct(
    const float* __restrict__ delays, const int* __restrict__ src,
    const int* __restrict__ net, const int* __restrict__ mask,
    float* __restrict__ out, int i) {
  const int p = blockIdx.x * blockDim.x + threadIdx.x;
  float* arr = out;
  float* req = out + LP;
  const int lf = i;
  const int lb = L - 1 - i;
  {
    const float d = delays[lf * P + p];
    const int2 s = *reinterpret_cast<const int2*>(src + (size_t)(lf - 1) * P * 2 + p * 2);
    const int2 n = *reinterpret_cast<const int2*>(net + (size_t)(lf - 1) * P * 2 + p * 2);
    const float* ap = arr + (lf - 1) * P;
    const float v0 = mask[n.x] ? NEGV : ap[s.x] + d;
    const float v1 = mask[n.y] ? NEGV : ap[s.y] + d;
    arr[lf * P + p] = fmaxf(fmaxf(v0, v1), d);
  }
  {
    const float c = req[(lb + 1) * P + p] - delays[(lb + 1) * P + p];
    const int2 s = *reinterpret_cast<const int2*>(src + (size_t)lb * P * 2 + p * 2);
    const int2 n = *reinterpret_cast<const int2*>(net + (size_t)lb * P * 2 + p * 2);
    float* rp = req + lb * P;
    if (!mask[n.x]) atomic_min_f32(rp + s.x, c);
    if (!mask[n.y]) atomic_min_f32(rp + s.y, c);
  }
}

// Epilogue: slack = required - arrival.
__global__ __launch_bounds__(256) void sta_slack(float* __restrict__ out) {
  int i4 = (blockIdx.x * blockDim.x + threadIdx.x) * 4;
  if (i4 < LP) {
    float4 a = *reinterpret_cast<const float4*>(out + i4);
    float4 r = *reinterpret_cast<const float4*>(out + LP + i4);
    float4 s = {r.x - a.x, r.y - a.y, r.z - a.z, r.w - a.w};
    *reinterpret_cast<float4*>(out + 2 * LP + i4) = s;
  }
}

extern "C" void kernel_launch(void* const* d_in, const int* in_sizes, int n_in,
                              void* d_out, int out_size, void* d_ws, size_t ws_size,
                              hipStream_t stream) {
  const float* delays = (const float*)d_in[0];
  const int* src = (const int*)d_in[1];
  const int* net = (const int*)d_in[2];
  const int* mask = (const int*)d_in[3];  // JAX bool delivered as int32
  float* out = (float*)d_out;
  int* esrc = (int*)d_ws;

  const bool use_esrc = ws_size >= (size_t)NARC * sizeof(int);

  sta_init<<<LP / 1024, 256, 0, stream>>>(delays, mask, out);
  if (use_esrc) {
    sta_pre<<<NARC / 4 / 256, 256, 0, stream>>>(src, net, mask, esrc);
    for (int i = 1; i < L; ++i) {
      sta_step<<<2 * P / 256, 256, 0, stream>>>(delays, esrc, out, i);
    }
  } else {
    for (int i = 1; i < L; ++i) {
      sta_step_direct<<<P / 256, 256, 0, stream>>>(delays, src, net, mask, out, i);
    }
  }
  sta_slack<<<LP / 1024, 256, 0, stream>>>(out);
}